// Round 18
// baseline (347.050 us; speedup 1.0000x reference)
//
#include <hip/hip_runtime.h>

#define NF 768
#define D1 10
#define D2 128
#define BM 32

typedef __attribute__((ext_vector_type(8))) short bf16x8;
typedef __attribute__((ext_vector_type(16))) float f32x16;

static __device__ __forceinline__ float sigf(float v){ return 1.0f/(1.0f+__expf(-v)); }
static __device__ __forceinline__ float tanhfast(float v){ return 2.0f/(1.0f+__expf(-2.0f*v)) - 1.0f; }
static __device__ __forceinline__ short f2bf(float f){
    unsigned u = __float_as_uint(f);
    u += 0x7fffu + ((u>>16)&1u);
    return (short)(u>>16);
}

static __device__ __forceinline__ short2 cvt2(float2 a){
    unsigned u;
    asm("v_cvt_pk_bf16_f32 %0, %1, %2" : "=v"(u) : "v"(a.x), "v"(a.y));
    union { unsigned uu; short2 s; } r; r.uu=u; return r.s;
}

// ---- degree counts ----
__global__ void k_deg(const int* __restrict__ dst, int* __restrict__ cnt, int E){
    int e = blockIdx.x*256 + threadIdx.x;
    if(e<E) atomicAdd(&cnt[dst[e]], 1);
}

// ---- scan + dinv, single block ----
__global__ __launch_bounds__(256) void k_scan(const int* __restrict__ cnt,
                                              int* __restrict__ rowptr, int* __restrict__ rowcur,
                                              float* __restrict__ dinv, int N, int E){
    __shared__ int part[256];
    int t = threadIdx.x;
    int C = (N+255)/256;
    int lo = t*C, hi = lo+C; if(hi>N) hi=N; if(lo>N) lo=N;
    int s=0;
    for(int i=lo;i<hi;i++) s += cnt[i];
    part[t]=s;
    __syncthreads();
    if(t==0){
        int run=0;
        for(int i=0;i<256;i++){ int v=part[i]; part[i]=run; run+=v; }
        rowptr[N]=E;
    }
    __syncthreads();
    int run = part[t];
    for(int i=lo;i<hi;i++){
        rowptr[i]=run; rowcur[i]=run; run += cnt[i];
        dinv[i] = rsqrtf((float)cnt[i] + 1.0f);
    }
}

__global__ void k_fill(const int* __restrict__ src, const int* __restrict__ dst,
                       const float* __restrict__ dinv, int* __restrict__ rowcur,
                       int* __restrict__ esrc, float* __restrict__ enorm, int E){
    int e = blockIdx.x*256 + threadIdx.x;
    if(e>=E) return;
    int s=src[e], d=dst[e];
    int pos = atomicAdd(&rowcur[d], 1);
    esrc[pos]=s;
    enorm[pos]=dinv[s]*dinv[d];
}

// ---- h1 = x @ W1 ----
__global__ __launch_bounds__(256) void k_h1(const float* __restrict__ x,
                                            const float* __restrict__ W1,
                                            float* __restrict__ h1, int N){
    __shared__ float wt[D1*NF];
    for(int idx=threadIdx.x; idx<NF*D1; idx+=256){
        int k=idx/D1, c=idx-k*D1;
        wt[c*NF+k]=W1[idx];
    }
    __syncthreads();
    int row = blockIdx.x*4 + (threadIdx.x>>6);
    int lane = threadIdx.x&63;
    if(row>=N) return;
    const float4* xr = (const float4*)(x + (size_t)row*NF);
    float acc[D1];
#pragma unroll
    for(int c=0;c<D1;c++) acc[c]=0.f;
#pragma unroll
    for(int i=0;i<3;i++){
        float4 v = xr[lane + 64*i];
#pragma unroll
        for(int c=0;c<D1;c++){
            float4 w = *(const float4*)&wt[c*NF + (lane+64*i)*4];
            acc[c] += v.x*w.x + v.y*w.y + v.z*w.z + v.w*w.w;
        }
    }
#pragma unroll
    for(int c=0;c<D1;c++){
        float v=acc[c];
#pragma unroll
        for(int off=32;off;off>>=1) v += __shfl_down(v,off,64);
        acc[c]=v;
    }
    if(lane==0){
#pragma unroll
        for(int c=0;c<D1;c++) h1[(size_t)row*D1+c]=acc[c];
    }
}

// ---- FUSED layer-1 gather + relu + hz = h @ W2 ----
__global__ __launch_bounds__(128) void k_gh(const float* __restrict__ h1,
        const int* __restrict__ rowptr, const int* __restrict__ esrc,
        const float* __restrict__ enorm, const float* __restrict__ dinv,
        const float* __restrict__ b1, const float* __restrict__ W2,
        float* __restrict__ hz, int N){
    __shared__ float w2s[D1*D2];
    int tid = threadIdx.x;
    for(int i=tid;i<D1*D2;i+=128) w2s[i]=W2[i];
    __syncthreads();
    int node = blockIdx.x*2 + (tid>>6);
    int lane = tid&63;
    if(node>=N) return;
    int e0=rowptr[node], e1=rowptr[node+1];
    float acc[D1];
#pragma unroll
    for(int c=0;c<D1;c++) acc[c]=0.f;
    for(int e=e0+lane; e<e1; e+=64){
        int s=esrc[e]; float w=enorm[e];
        const float* hr = h1 + (size_t)s*D1;
#pragma unroll
        for(int c=0;c<D1;c++) acc[c] += hr[c]*w;
    }
#pragma unroll
    for(int c=0;c<D1;c++){
        float v=acc[c];
#pragma unroll
        for(int off=32;off;off>>=1) v += __shfl_down(v,off,64);
        acc[c] = __shfl(v, 0, 64);
    }
    float di=dinv[node], d2=di*di;
    const float* hr = h1 + (size_t)node*D1;
    float h[D1];
#pragma unroll
    for(int c=0;c<D1;c++){
        float v = acc[c] + hr[c]*d2 + b1[c];
        h[c] = v>0.f ? v : 0.f;
    }
    float o0=0.f, o1=0.f;
#pragma unroll
    for(int k=0;k<D1;k++){
        o0 += h[k]*w2s[k*D2 + lane];
        o1 += h[k]*w2s[k*D2 + 64 + lane];
    }
    hz[(size_t)node*D2 + lane]      = o0;
    hz[(size_t)node*D2 + 64 + lane] = o1;
}

// ---- layer-2 CSR gather (fused zfin), fp32 z table ----
__global__ __launch_bounds__(128) void k_gath2(const float* __restrict__ hz,
        const int* __restrict__ rowptr, const int* __restrict__ esrc,
        const float* __restrict__ enorm, const float* __restrict__ dinv,
        const float* __restrict__ b2, float* __restrict__ zbf, int N){
    int n = blockIdx.x;
    int c = threadIdx.x;
    int e0 = rowptr[n], e1 = rowptr[n+1];
    float di = dinv[n];
    float acc = hz[(size_t)n*D2+c]*di*di + b2[c];
    int e = e0;
    for(; e+1<e1; e+=2){
        int s0=esrc[e], s1=esrc[e+1];
        float w0=enorm[e], w1=enorm[e+1];
        acc += hz[(size_t)s0*D2+c]*w0 + hz[(size_t)s1*D2+c]*w1;
    }
    if(e<e1) acc += hz[(size_t)esrc[e]*D2+c]*enorm[e];
    zbf[(size_t)n*D2+c] = acc;
}

// ---- B fragment image K=1024 (+ zero cnt): 12 frags x 64 ks16 x 64 x 8 ----
__global__ void k_wimgB(const float* __restrict__ Wih, ushort* __restrict__ img,
                        int* __restrict__ cnt, int N){
    int gid = blockIdx.x*256 + threadIdx.x;        // 12*64*64 = 49152
    if(gid < N) cnt[gid] = 0;
    if(gid >= 12*64*64) return;
    int l = gid & 63;
    int ks16 = (gid>>6) & 63;
    int f = gid >> 12;
    int dd = l & 31, kb = l>>5;
    int wn = f/3, gi = f - wn*3;
    int gbase = (gi==0)?0:((gi==1)?256:384);
    int wrow = gbase + wn*32 + dd;
    int k = ks16*16 + kb*8;
    const float* p = Wih + (size_t)wrow*1024 + k;
    float4 v0=*(const float4*)p, v1=*(const float4*)(p+4);
    ushort o[8];
    o[0]=f2bf(v0.x); o[1]=f2bf(v0.y); o[2]=f2bf(v0.z); o[3]=f2bf(v0.w);
    o[4]=f2bf(v1.x); o[5]=f2bf(v1.y); o[6]=f2bf(v1.z); o[7]=f2bf(v1.w);
    *(int4*)(img + (size_t)gid*8) = *(int4*)o;
}

// ---- fused MFMA GEMM + LSTM partials. BM=32: one 32x32 A-frag per step,
// acc = 48 AGPR/wave -> 3 blocks/CU (12 waves, desynchronized barriers).
// B: direct L2->register ring-2 (r17). A: float2 reg ring-4 -> cvt_pk ->
// conflict-free LDS ring-3 (3x1KB). One raw barrier + lgkmcnt per step. ----
__global__ __launch_bounds__(256,3) void k_big(
    const float* __restrict__ remb, const ushort* __restrict__ img,
    const float* __restrict__ zbf, const float* __restrict__ b_ih,
    const float* __restrict__ b_hh, const int* __restrict__ trip,
    float* __restrict__ rowacc, int T)
{
    __shared__ ushort Ab[3][2*32*8];     // 3 x 1 KB: [ring][kh*32+row][8 bf16]
    int tid=threadIdx.x, lane=tid&63, w=tid>>6;
    int l31=lane&31, lh=lane>>5;
    int t0=blockIdx.x*BM;

    // A staging: row = tid>>3 (0..31), seg = tid&7 (8B = 2 floats of the 16-k slice)
    const int arow = tid>>3;
    const int aseg = tid&7;
    int tc = t0 + arow; if(tc>=T) tc=T-1;
    const float* pzh = zbf + (size_t)trip[3*tc]*D2   + aseg*2;
    const float* prm = remb + (size_t)tc*NF          + aseg*2;
    const float* pzt = zbf + (size_t)trip[3*tc+2]*D2 + aseg*2;
    const int awoff = ((aseg>>2)*32 + arow)*8 + (aseg&3)*2;   // ushort units
    const int ar = (lh*32 + l31)*8;                           // lane-linear read

    const ushort* wb0 = img + ((size_t)((w*3+0)*64)*64 + lane)*8;
    const ushort* wb1 = img + ((size_t)((w*3+1)*64)*64 + lane)*8;
    const ushort* wb2 = img + ((size_t)((w*3+2)*64)*64 + lane)*8;

    const f32x16 zer = {0,0,0,0,0,0,0,0,0,0,0,0,0,0,0,0};
    f32x16 acc0=zer, acc1=zer, acc2=zer;

    float2 pa[4];
    bf16x8 qb[2][3];

#define ALOAD(C_) if((C_)<64){ \
    const float* s_; \
    if((C_)<8)       s_ = pzh + (C_)*16; \
    else if((C_)<56) s_ = prm + ((C_)-8)*16; \
    else             s_ = pzt + ((C_)-56)*16; \
    pa[(C_)&3] = *(const float2*)s_; }

#define AWRITE(C_) if((C_)<64){ \
    *(short2*)&Ab[(C_)%3][awoff] = cvt2(pa[(C_)&3]); }

#define BLOAD(C_) if((C_)<64){ \
    qb[(C_)&1][0] = *(const bf16x8*)(wb0 + (size_t)(C_)*512); \
    qb[(C_)&1][1] = *(const bf16x8*)(wb1 + (size_t)(C_)*512); \
    qb[(C_)&1][2] = *(const bf16x8*)(wb2 + (size_t)(C_)*512); }

#define CH(C_) { \
    BLOAD((C_)+1) \
    ALOAD((C_)+4) \
    __builtin_amdgcn_sched_barrier(0); \
    AWRITE((C_)+1) \
    asm volatile("s_waitcnt lgkmcnt(0)" ::: "memory"); \
    __builtin_amdgcn_s_barrier(); \
    __builtin_amdgcn_sched_barrier(0); \
    { \
        bf16x8 A_ = *(const bf16x8*)&Ab[(C_)%3][ar]; \
        bf16x8 B0_ = qb[(C_)&1][0]; \
        bf16x8 B1_ = qb[(C_)&1][1]; \
        bf16x8 B2_ = qb[(C_)&1][2]; \
        __builtin_amdgcn_s_setprio(1); \
        acc0=__builtin_amdgcn_mfma_f32_32x32x16_bf16(A_,B0_,acc0,0,0,0); \
        acc1=__builtin_amdgcn_mfma_f32_32x32x16_bf16(A_,B1_,acc1,0,0,0); \
        acc2=__builtin_amdgcn_mfma_f32_32x32x16_bf16(A_,B2_,acc2,0,0,0); \
        __builtin_amdgcn_s_setprio(0); \
    } \
}

    // prologue: A(0..3) in regs, B(0), write A(0) into Ab[0]
    ALOAD(0) ALOAD(1) ALOAD(2) ALOAD(3)
    __builtin_amdgcn_sched_barrier(0);
    BLOAD(0)
    __builtin_amdgcn_sched_barrier(0);
    AWRITE(0)

    CH(0)  CH(1)  CH(2)  CH(3)  CH(4)  CH(5)  CH(6)  CH(7)
    CH(8)  CH(9)  CH(10) CH(11) CH(12) CH(13) CH(14) CH(15)
    CH(16) CH(17) CH(18) CH(19) CH(20) CH(21) CH(22) CH(23)
    CH(24) CH(25) CH(26) CH(27) CH(28) CH(29) CH(30) CH(31)
    CH(32) CH(33) CH(34) CH(35) CH(36) CH(37) CH(38) CH(39)
    CH(40) CH(41) CH(42) CH(43) CH(44) CH(45) CH(46) CH(47)
    CH(48) CH(49) CH(50) CH(51) CH(52) CH(53) CH(54) CH(55)
    CH(56) CH(57) CH(58) CH(59) CH(60) CH(61) CH(62) CH(63)
#undef CH
#undef BLOAD
#undef AWRITE
#undef ALOAD

    // ---- epilogue: bias + LSTM + partial row-sums (global atomics) ----
    int d = w*32+l31;
    float bi=b_ih[d]+b_hh[d];
    float bg=b_ih[256+d]+b_hh[256+d];
    float bo=b_ih[384+d]+b_hh[384+d];
#pragma unroll
    for(int r=0;r<16;r++){
        int row = (r&3)+8*(r>>2)+4*lh;
        int t = t0+row;
        float ov = 0.f;
        if(t<T){
            float ig = acc0[r] + bi;
            float gg = acc1[r] + bg;
            float og = acc2[r] + bo;
            float cc = sigf(ig)*tanhfast(gg);
            ov = sigf(og)*tanhfast(cc);
        }
#pragma unroll
        for(int off=1; off<32; off<<=1) ov += __shfl_xor(ov, off, 64);
        if(l31==0 && t<T) atomicAdd(&rowacc[t], ov);
    }
}

__global__ void k_sig(const float* __restrict__ rowacc, float* __restrict__ score, int T){
    int t = blockIdx.x*256 + threadIdx.x;
    if(t<T) score[t] = sigf(rowacc[t]);
}

extern "C" void kernel_launch(void* const* d_in, const int* in_sizes, int n_in,
                              void* d_out, int out_size, void* d_ws, size_t ws_size,
                              hipStream_t stream){
    const float* x    = (const float*)d_in[0];
    const float* remb = (const float*)d_in[1];
    const float* W1   = (const float*)d_in[2];
    const float* b1   = (const float*)d_in[3];
    const float* W2   = (const float*)d_in[4];
    const float* b2   = (const float*)d_in[5];
    const float* Wih  = (const float*)d_in[6];
    const float* b_ih = (const float*)d_in[8];
    const float* b_hh = (const float*)d_in[9];
    const int*   ei   = (const int*)d_in[10];
    const int*   trip = (const int*)d_in[11];
    float* score = (float*)d_out;

    const int N = in_sizes[0]/NF;       // 15000
    const int E = in_sizes[10]/2;       // 200000
    const int T = in_sizes[11]/3;       // 100000
    const int* src = ei;
    const int* dst = ei + E;

    float* ws = (float*)d_ws;
    size_t o = 0;
    ushort* img   = (ushort*)(ws+o); o += (size_t)12*64*64*8/2;  // 786 KB
    float* zbf    = ws+o;            o += (size_t)N*D2;          // fp32 z
    float* rowacc = ws+o;            o += (size_t)((T+7)&~7);
    int*   cnt    = (int*)(ws+o);    o += (size_t)((N+8)&~7);
    int*   rowptr = (int*)(ws+o);    o += (size_t)((N+8)&~7);
    int*   rowcur = (int*)(ws+o);    o += (size_t)((N+8)&~7);
    int*   esrc   = (int*)(ws+o);    o += (size_t)E;
    float* enorm  = ws+o;            o += (size_t)E;
    float* dinv   = ws+o;            o += (size_t)((N+7)&~7);
    float* h1     = ws+o;            o += (size_t)N*D1;
    float* hz     = ws+o;            o += (size_t)N*D2;
    (void)ws_size; (void)n_in; (void)out_size;

    hipMemsetAsync(rowacc, 0, (size_t)T*sizeof(float), stream);

    k_wimgB<<<dim3((12*64*64+255)/256), dim3(256), 0, stream>>>(Wih, img, cnt, N);
    k_deg  <<<dim3((E+255)/256), dim3(256), 0, stream>>>(dst, cnt, E);
    k_scan <<<dim3(1), dim3(256), 0, stream>>>(cnt, rowptr, rowcur, dinv, N, E);
    k_fill <<<dim3((E+255)/256), dim3(256), 0, stream>>>(src, dst, dinv, rowcur, esrc, enorm, E);
    k_h1   <<<dim3((N+3)/4), dim3(256), 0, stream>>>(x, W1, h1, N);
    k_gh   <<<dim3((N+1)/2), dim3(128), 0, stream>>>(h1, rowptr, esrc, enorm, dinv, b1, W2, hz, N);
    k_gath2<<<dim3(N), dim3(128), 0, stream>>>(hz, rowptr, esrc, enorm, dinv, b2, zbf, N);
    k_big  <<<dim3((T+BM-1)/BM), dim3(256), 0, stream>>>(remb, img, zbf, b_ih, b_hh, trip, rowacc, T);
    k_sig  <<<dim3((T+255)/256), dim3(256), 0, stream>>>(rowacc, score, T);
}